// Round 2
// baseline (57.391 us; speedup 1.0000x reference)
//
#include <hip/hip_runtime.h>

#define EPSF 1e-7f

__device__ __forceinline__ float rcp_fast(float x) { return __builtin_amdgcn_rcpf(x); }

// Kernel 1: x2[j] = ||x_j||^2
__global__ void x2_kernel(const float* __restrict__ x, float* __restrict__ x2, int N) {
    int j = blockIdx.x * blockDim.x + threadIdx.x;
    if (j < N) {
        const float4* row = reinterpret_cast<const float4*>(x + (size_t)j * 64);
        float s = 0.f;
#pragma unroll
        for (int c = 0; c < 16; ++c) {
            float4 v = row[c];
            s += v.x * v.x + v.y * v.y + v.z * v.z + v.w * v.w;
        }
        x2[j] = s;
    }
}

// Kernel 2: one block per 2 rows (i0, i1). 256 threads; thread t -> (jl = t>>1, h = t&1).
// j-tiles of 128 rows staged to LDS with coalesced loads + XOR chunk swizzle;
// each staged tile is consumed for BOTH output rows (halves LDS reads + L2 fetch).
__global__ __launch_bounds__(256, 2) void agg_kernel(
    const float* __restrict__ x, const int* __restrict__ adj,
    const float* __restrict__ x2ws, float* __restrict__ out) {
    const int N = 1024, D = 64;
    const int i0 = blockIdx.x * 2;
    const int i1 = i0 + 1;
    const int t = threadIdx.x;
    const int jl = t >> 1;   // 0..127
    const int h = t & 1;     // d-half
    const int lane = t & 63;
    const int w = t >> 6;

    __shared__ float4 tile4[128 * 16];     // 32 KB, XOR-swizzled chunks
    __shared__ float red[2][32][65];       // padded: stride 65 -> 2-way max
    __shared__ float alpha_buf[2][32];

    // xi halves for both rows (broadcast loads, cached)
    float xi0[32], xi1[32];
    {
        const float4* p0 = reinterpret_cast<const float4*>(x + (size_t)i0 * D + h * 32);
        const float4* p1 = reinterpret_cast<const float4*>(x + (size_t)i1 * D + h * 32);
#pragma unroll
        for (int c = 0; c < 8; ++c) {
            float4 v = p0[c];
            xi0[4 * c + 0] = v.x; xi0[4 * c + 1] = v.y; xi0[4 * c + 2] = v.z; xi0[4 * c + 3] = v.w;
            float4 u = p1[c];
            xi1[4 * c + 0] = u.x; xi1[4 * c + 1] = u.y; xi1[4 * c + 2] = u.z; xi1[4 * c + 3] = u.w;
        }
    }
    const float x2i0 = x2ws[i0], x2i1 = x2ws[i1];
    const float onemx2_0 = 1.f - x2i0, onemx2c_0 = fmaxf(onemx2_0, EPSF);
    const float onemx2_1 = 1.f - x2i1, onemx2c_1 = fmaxf(onemx2_1, EPSF);

    float acc0[32], acc1[32];
#pragma unroll
    for (int k = 0; k < 32; ++k) { acc0[k] = 0.f; acc1[k] = 0.f; }
    float alpha0 = 0.f, alpha1 = 0.f;

    const float4* xg4 = reinterpret_cast<const float4*>(x);
    float4 stg[8];
    // prologue: tile 0 into registers (coalesced: lane-consecutive float4s)
#pragma unroll
    for (int r = 0; r < 8; ++r) stg[r] = xg4[r * 256 + t];

    for (int tile = 0; tile < 8; ++tile) {
        // store staged regs -> LDS with XOR chunk swizzle
#pragma unroll
        for (int r = 0; r < 8; ++r) {
            const int fl = r * 256 + t;
            const int rr = fl >> 4;
            const int c = t & 15;
            tile4[rr * 16 + (c ^ (rr & 15))] = stg[r];
        }
        __syncthreads();
        if (tile < 7) {
#pragma unroll
            for (int r = 0; r < 8; ++r) stg[r] = xg4[(tile + 1) * 2048 + r * 256 + t];
        }

        const int j = tile * 128 + jl;
        const int m0 = adj[(size_t)i0 * N + j];
        const int m1 = adj[(size_t)i1 * N + j];
        const float y2 = x2ws[j];

        float xj[32];
#pragma unroll
        for (int c = 0; c < 8; ++c) {
            float4 v = tile4[jl * 16 + ((h * 8 + c) ^ (jl & 15))];
            xj[4 * c + 0] = v.x; xj[4 * c + 1] = v.y; xj[4 * c + 2] = v.z; xj[4 * c + 3] = v.w;
        }

        // dots for both rows, 4-way ILP
        float a0 = 0.f, b0 = 0.f, c0 = 0.f, d0 = 0.f;
        float a1 = 0.f, b1 = 0.f, c1p = 0.f, d1 = 0.f;
#pragma unroll
        for (int k = 0; k < 32; k += 4) {
            a0 = fmaf(xi0[k + 0], xj[k + 0], a0);
            b0 = fmaf(xi0[k + 1], xj[k + 1], b0);
            c0 = fmaf(xi0[k + 2], xj[k + 2], c0);
            d0 = fmaf(xi0[k + 3], xj[k + 3], d0);
            a1 = fmaf(xi1[k + 0], xj[k + 0], a1);
            b1 = fmaf(xi1[k + 1], xj[k + 1], b1);
            c1p = fmaf(xi1[k + 2], xj[k + 2], c1p);
            d1 = fmaf(xi1[k + 3], xj[k + 3], d1);
        }
        float dp0 = (a0 + b0) + (c0 + d0);
        float dp1 = (a1 + b1) + (c1p + d1);
        const float dot0 = dp0 + __shfl_xor(dp0, 1, 64);
        const float dot1 = dp1 + __shfl_xor(dp1, 1, 64);

        float sv0, tv0, sv1, tv1;
        {
            const float c1 = fmaf(-2.f, dot0, 1.f);
            const float A = c1 + y2;
            const float den = fmaxf(fmaf(x2i0, y2, c1), EPSF);
            const float rd = rcp_fast(den);
            const float a = -A * rd;
            const float bb = onemx2_0 * rd;
            float un2 = a * a * x2i0;
            un2 = fmaf(bb * bb, y2, un2);
            un2 = fmaf(2.f * a * bb, dot0, un2);
            un2 = fmaxf(un2, 0.f);
            float un = sqrtf(un2);
            un = fminf(fmaxf(un, EPSF), 1.0f - 1e-5f);
            const float ratio = (1.f + un) * rcp_fast(1.f - un);
            const float at = 0.34657359027997264f * __log2f(ratio);
            const float g = onemx2c_0 * at * rcp_fast(un);
            sv0 = m0 ? g * a : 0.f;
            tv0 = m0 ? g * bb : 0.f;
        }
        {
            const float c1 = fmaf(-2.f, dot1, 1.f);
            const float A = c1 + y2;
            const float den = fmaxf(fmaf(x2i1, y2, c1), EPSF);
            const float rd = rcp_fast(den);
            const float a = -A * rd;
            const float bb = onemx2_1 * rd;
            float un2 = a * a * x2i1;
            un2 = fmaf(bb * bb, y2, un2);
            un2 = fmaf(2.f * a * bb, dot1, un2);
            un2 = fmaxf(un2, 0.f);
            float un = sqrtf(un2);
            un = fminf(fmaxf(un, EPSF), 1.0f - 1e-5f);
            const float ratio = (1.f + un) * rcp_fast(1.f - un);
            const float at = 0.34657359027997264f * __log2f(ratio);
            const float g = onemx2c_1 * at * rcp_fast(un);
            sv1 = m1 ? g * a : 0.f;
            tv1 = m1 ? g * bb : 0.f;
        }
        alpha0 += (h == 0) ? sv0 : 0.f;
        alpha1 += (h == 0) ? sv1 : 0.f;
#pragma unroll
        for (int k = 0; k < 32; ++k) {
            acc0[k] = fmaf(tv0, xj[k], acc0[k]);
            acc1[k] = fmaf(tv1, xj[k], acc1[k]);
        }
        __syncthreads();
    }

    // partial butterfly (offsets 2,4): quad sums land on lanes with (lane&7)<2
#pragma unroll
    for (int off = 2; off <= 4; off <<= 1) {
#pragma unroll
        for (int k = 0; k < 32; ++k) {
            acc0[k] += __shfl_xor(acc0[k], off, 64);
            acc1[k] += __shfl_xor(acc1[k], off, 64);
        }
        alpha0 += __shfl_xor(alpha0, off, 64);
        alpha1 += __shfl_xor(alpha1, off, 64);
    }
    if ((lane & 7) < 2) {
        const int quad = w * 8 + (lane >> 3);
#pragma unroll
        for (int k = 0; k < 32; ++k) {
            red[0][quad][h * 32 + k] = acc0[k];
            red[1][quad][h * 32 + k] = acc1[k];
        }
        if ((lane & 7) == 0) { alpha_buf[0][quad] = alpha0; alpha_buf[1][quad] = alpha1; }
    }
    __syncthreads();

    if (t < 128) {
        const int r = t >> 6;   // wave0 -> row i0, wave1 -> row i1
        const int d = t & 63;
        const int i = i0 + r;
        float v = 0.f;
#pragma unroll
        for (int q = 0; q < 32; ++q) v += red[r][q][d];
        float alph = 0.f;
#pragma unroll
        for (int q = 0; q < 32; ++q) alph += alpha_buf[r][q];

        const float x2i = r ? x2i1 : x2i0;
        const float onemx2 = 1.f - x2i;
        const float onemx2c = fmaxf(onemx2, EPSF);
        const float xid = x[(size_t)i * D + d];
        v = fmaf(alph, xid, v);

        // expmap(v, xi)
        float vn2 = v * v;
#pragma unroll
        for (int off = 1; off < 64; off <<= 1) vn2 += __shfl_xor(vn2, off, 64);
        const float vn = fmaxf(sqrtf(vn2), EPSF);
        const float arg = vn * rcp_fast(onemx2c);
        const float th = tanhf(arg);
        const float sec = th * rcp_fast(vn) * v;

        // mobius_add(xi, second)
        float xy = xid * sec;
        float y2p = sec * sec;
#pragma unroll
        for (int off = 1; off < 64; off <<= 1) {
            xy += __shfl_xor(xy, off, 64);
            y2p += __shfl_xor(y2p, off, 64);
        }
        const float numd = (1.f + 2.f * xy + y2p) * xid + onemx2 * sec;
        const float den2 = fmaxf(fmaf(x2i, y2p, 1.f + 2.f * xy), EPSF);
        out[(size_t)i * D + d] = numd * rcp_fast(den2);
    }
}

extern "C" void kernel_launch(void* const* d_in, const int* in_sizes, int n_in,
                              void* d_out, int out_size, void* d_ws, size_t ws_size,
                              hipStream_t stream) {
    const float* x = (const float*)d_in[0];
    const int* adj = (const int*)d_in[1];
    float* out = (float*)d_out;
    float* x2 = (float*)d_ws;
    const int N = 1024;

    hipLaunchKernelGGL(x2_kernel, dim3(N / 256), dim3(256), 0, stream, x, x2, N);
    hipLaunchKernelGGL(agg_kernel, dim3(N / 2), dim3(256), 0, stream, x, adj, x2, out);
}

// Round 3
// 42.125 us; speedup vs baseline: 1.3624x; 1.3624x over previous
//
#include <hip/hip_runtime.h>

#define EPSF 1e-7f

__device__ __forceinline__ float rcp_fast(float x) { return __builtin_amdgcn_rcpf(x); }

// K1: x2[j] = ||x_j||^2
__global__ void x2_kernel(const float* __restrict__ x, float* __restrict__ x2) {
    int j = blockIdx.x * blockDim.x + threadIdx.x;
    const float4* row = reinterpret_cast<const float4*>(x + (size_t)j * 64);
    float s = 0.f;
#pragma unroll
    for (int c = 0; c < 16; ++c) {
        float4 v = row[c];
        s += v.x * v.x + v.y * v.y + v.z * v.z + v.w * v.w;
    }
    x2[j] = s;
}

// K2: 64x64 tile per block; 4x4 micro-tile per thread. Gram from global (L1),
// scalar map -> T[i*N+j], alpha partials -> alphaPart[jt*N+i]. No LDS.
__global__ __launch_bounds__(256) void pair_kernel(
    const float* __restrict__ x, const int* __restrict__ adj,
    const float* __restrict__ x2ws, float* __restrict__ T,
    float* __restrict__ alphaPart) {
    const int N = 1024;
    const int j0 = blockIdx.x * 64;
    const int i0 = blockIdx.y * 64;
    const int t = threadIdx.x;
    const int tx = t & 15;       // j quad
    const int ty = t >> 4;       // i quad
    const int ib = i0 + ty * 4;
    const int jb = j0 + tx * 4;

    float acc[4][4];
#pragma unroll
    for (int a = 0; a < 4; ++a)
#pragma unroll
        for (int b = 0; b < 4; ++b) acc[a][b] = 0.f;

    const float4* x4 = reinterpret_cast<const float4*>(x);
#pragma unroll
    for (int c = 0; c < 16; ++c) {
        float4 xiv[4], xjv[4];
#pragma unroll
        for (int a = 0; a < 4; ++a) xiv[a] = x4[(size_t)(ib + a) * 16 + c];
#pragma unroll
        for (int b = 0; b < 4; ++b) xjv[b] = x4[(size_t)(jb + b) * 16 + c];
#pragma unroll
        for (int a = 0; a < 4; ++a)
#pragma unroll
            for (int b = 0; b < 4; ++b) {
                acc[a][b] = fmaf(xiv[a].x, xjv[b].x, acc[a][b]);
                acc[a][b] = fmaf(xiv[a].y, xjv[b].y, acc[a][b]);
                acc[a][b] = fmaf(xiv[a].z, xjv[b].z, acc[a][b]);
                acc[a][b] = fmaf(xiv[a].w, xjv[b].w, acc[a][b]);
            }
    }

    float x2i[4], y2[4];
#pragma unroll
    for (int a = 0; a < 4; ++a) x2i[a] = x2ws[ib + a];
#pragma unroll
    for (int b = 0; b < 4; ++b) y2[b] = x2ws[jb + b];

    float svsum[4];
#pragma unroll
    for (int a = 0; a < 4; ++a) {
        const int4 aj = *reinterpret_cast<const int4*>(&adj[(size_t)(ib + a) * N + jb]);
        const int m[4] = {aj.x, aj.y, aj.z, aj.w};
        const float onemx2 = 1.f - x2i[a];
        const float onemx2c = fmaxf(onemx2, EPSF);
        float tv4[4];
        float ssum = 0.f;
#pragma unroll
        for (int b = 0; b < 4; ++b) {
            const float dot = acc[a][b];
            const float c1 = fmaf(-2.f, dot, 1.f);
            const float A = c1 + y2[b];
            const float den = fmaxf(fmaf(x2i[a], y2[b], c1), EPSF);
            const float rd = rcp_fast(den);
            const float av = -A * rd;
            const float bv = onemx2 * rd;
            float un2 = av * av * x2i[a];
            un2 = fmaf(bv * bv, y2[b], un2);
            un2 = fmaf(2.f * av * bv, dot, un2);
            un2 = fmaxf(un2, 0.f);
            float un = sqrtf(un2);
            un = fminf(fmaxf(un, EPSF), 1.0f - 1e-5f);
            const float ratio = (1.f + un) * rcp_fast(1.f - un);
            const float at = 0.34657359027997264f * __log2f(ratio);  // atanh(un)
            const float g = onemx2c * at * rcp_fast(un);
            const float sv = m[b] ? g * av : 0.f;
            const float tv = m[b] ? g * bv : 0.f;
            ssum += sv;
            tv4[b] = tv;
        }
        float4 tw = {tv4[0], tv4[1], tv4[2], tv4[3]};
        *reinterpret_cast<float4*>(&T[(size_t)(ib + a) * N + jb]) = tw;
        svsum[a] = ssum;
    }

    // reduce alpha partials across tx (lane bits 0..3)
#pragma unroll
    for (int off = 1; off <= 8; off <<= 1) {
#pragma unroll
        for (int a = 0; a < 4; ++a) svsum[a] += __shfl_xor(svsum[a], off, 64);
    }
    if (tx == 0) {
#pragma unroll
        for (int a = 0; a < 4; ++a)
            alphaPart[(size_t)blockIdx.x * N + ib + a] = svsum[a];
    }
}

// K3: one wave per row i: v = T[i,:]*X (scalar T loads, lane-d X loads),
// + alpha*x_i, then expmap. No LDS; shuffle reductions only.
__global__ __launch_bounds__(256) void out_kernel(
    const float* __restrict__ x, const float* __restrict__ T,
    const float* __restrict__ alphaPart, float* __restrict__ out) {
    const int N = 1024, D = 64;
    const int w = threadIdx.x >> 6;
    const int d = threadIdx.x & 63;
    const int i = __builtin_amdgcn_readfirstlane(blockIdx.x * 4 + w);

    const float xid = x[(size_t)i * D + d];
    float x2i = xid * xid;
#pragma unroll
    for (int off = 1; off < 64; off <<= 1) x2i += __shfl_xor(x2i, off, 64);
    const float onemx2 = 1.f - x2i;
    const float onemx2c = fmaxf(onemx2, EPSF);

    const float4* Tr = reinterpret_cast<const float4*>(T + (size_t)i * N);
    float v0 = 0.f, v1 = 0.f, v2 = 0.f, v3 = 0.f;
    for (int jb = 0; jb < 256; jb += 4) {  // 16 j per iteration
        float4 t0 = Tr[jb + 0];
        float4 t1 = Tr[jb + 1];
        float4 t2 = Tr[jb + 2];
        float4 t3 = Tr[jb + 3];
        const float* xp = x + (size_t)jb * 4 * D + d;
        v0 = fmaf(t0.x, xp[0 * D], v0);
        v1 = fmaf(t0.y, xp[1 * D], v1);
        v2 = fmaf(t0.z, xp[2 * D], v2);
        v3 = fmaf(t0.w, xp[3 * D], v3);
        v0 = fmaf(t1.x, xp[4 * D], v0);
        v1 = fmaf(t1.y, xp[5 * D], v1);
        v2 = fmaf(t1.z, xp[6 * D], v2);
        v3 = fmaf(t1.w, xp[7 * D], v3);
        v0 = fmaf(t2.x, xp[8 * D], v0);
        v1 = fmaf(t2.y, xp[9 * D], v1);
        v2 = fmaf(t2.z, xp[10 * D], v2);
        v3 = fmaf(t2.w, xp[11 * D], v3);
        v0 = fmaf(t3.x, xp[12 * D], v0);
        v1 = fmaf(t3.y, xp[13 * D], v1);
        v2 = fmaf(t3.z, xp[14 * D], v2);
        v3 = fmaf(t3.w, xp[15 * D], v3);
    }
    float v = (v0 + v1) + (v2 + v3);

    // alpha = sum of 16 partials
    float ap = (d < 16) ? alphaPart[(size_t)d * N + i] : 0.f;
#pragma unroll
    for (int off = 1; off < 64; off <<= 1) ap += __shfl_xor(ap, off, 64);
    v = fmaf(ap, xid, v);

    // expmap(v, x_i)
    float vn2 = v * v;
#pragma unroll
    for (int off = 1; off < 64; off <<= 1) vn2 += __shfl_xor(vn2, off, 64);
    const float vn = fmaxf(sqrtf(vn2), EPSF);
    const float arg = vn * rcp_fast(onemx2c);
    const float th = tanhf(arg);
    const float sec = th * rcp_fast(vn) * v;

    // mobius_add(x_i, sec)
    float xy = xid * sec;
    float y2p = sec * sec;
#pragma unroll
    for (int off = 1; off < 64; off <<= 1) {
        xy += __shfl_xor(xy, off, 64);
        y2p += __shfl_xor(y2p, off, 64);
    }
    const float numd = (1.f + 2.f * xy + y2p) * xid + onemx2 * sec;
    const float den2 = fmaxf(fmaf(x2i, y2p, 1.f + 2.f * xy), EPSF);
    out[(size_t)i * D + d] = numd * rcp_fast(den2);
}

extern "C" void kernel_launch(void* const* d_in, const int* in_sizes, int n_in,
                              void* d_out, int out_size, void* d_ws, size_t ws_size,
                              hipStream_t stream) {
    const float* x = (const float*)d_in[0];
    const int* adj = (const int*)d_in[1];
    float* out = (float*)d_out;
    const int N = 1024;

    float* T = (float*)d_ws;                                  // 4 MB
    float* alphaPart = (float*)((char*)d_ws + (size_t)N * N * 4);  // 64 KB
    float* x2 = (float*)((char*)d_ws + (size_t)N * N * 4 + 16 * N * 4);

    hipLaunchKernelGGL(x2_kernel, dim3(N / 256), dim3(256), 0, stream, x, x2);
    hipLaunchKernelGGL(pair_kernel, dim3(16, 16), dim3(256), 0, stream, x, adj, x2, T, alphaPart);
    hipLaunchKernelGGL(out_kernel, dim3(N / 4), dim3(256), 0, stream, x, T, alphaPart, out);
}